// Round 1
// baseline (187.427 us; speedup 1.0000x reference)
//
#include <hip/hip_runtime.h>

#define B_DIM   128
#define S_DIM   4096
#define N_TOK   (B_DIM * S_DIM)
#define HID     32
#define D_IN    9

// tanh(x) = (e^{2x}-1)/(e^{2x}+1); clamp so exp never overflows (tanh(9) rounds to 1.0f)
__device__ __forceinline__ float fast_tanh(float x) {
    float xc = fminf(fmaxf(x, -9.0f), 9.0f);
    float e2 = __expf(2.0f * xc);
    return __fdividef(e2 - 1.0f, e2 + 1.0f);
}

// -------- Kernel 1: per-batch inclusive prefix sum of delta_x[..., 2] + init_temp --------
// grid = 128 (one block per batch), block = 1024 threads (16 waves), 4 chunks of 1024.
__global__ __launch_bounds__(1024) void cumsum_kernel(const float* __restrict__ dx,
                                                      float* __restrict__ temp) {
    const int b    = blockIdx.x;
    const int tid  = threadIdx.x;
    const int lane = tid & 63;
    const int wid  = tid >> 6;
    __shared__ float wsum[16];

    const float* base = dx + (size_t)b * S_DIM * 6;
    const float init_temp = base[5];        // delta_x[b, 0, 5]
    float carry = 0.0f;

    #pragma unroll
    for (int c = 0; c < 4; ++c) {
        const int s = c * 1024 + tid;
        float x = base[(size_t)s * 6 + 2];

        // wave-level inclusive scan (64 lanes)
        #pragma unroll
        for (int off = 1; off < 64; off <<= 1) {
            float y = __shfl_up(x, off, 64);
            if (lane >= off) x += y;
        }
        if (lane == 63) wsum[wid] = x;      // wave total
        __syncthreads();

        float prefix = carry;
        float total  = 0.0f;
        #pragma unroll
        for (int w = 0; w < 16; ++w) {
            float wv = wsum[w];
            if (w < wid) prefix += wv;
            total += wv;
        }
        temp[(size_t)b * S_DIM + s] = x + prefix + init_temp;
        carry += total;
        __syncthreads();
    }
}

// -------- Kernel 2: fully parallel per-token MLP + gate --------
__global__ __launch_bounds__(256) void msc_kernel(
    const float* __restrict__ h_prev, const float* __restrict__ dx,
    const float* __restrict__ temp,
    const float* __restrict__ Wa0, const float* __restrict__ ba0,
    const float* __restrict__ Wb0, const float* __restrict__ bb0,
    const float* __restrict__ Wa1, const float* __restrict__ ba1,
    const float* __restrict__ Wb1, const float* __restrict__ bb1,
    const float* __restrict__ W_alpha, const float* __restrict__ b_alpha,
    const float* __restrict__ W_beta,  const float* __restrict__ b_beta,
    const float* __restrict__ W_gamma, const float* __restrict__ b_gamma,
    const float* __restrict__ W_c,     const float* __restrict__ b_c,
    const float* __restrict__ W_out,
    float* __restrict__ out)
{
    const int t = blockIdx.x * 256 + threadIdx.x;
    if (t >= N_TOK) return;

    const float* hp = h_prev + (size_t)t * 5;
    const float* d  = dx     + (size_t)t * 6;

    const float df0 = d[0], df1 = d[1], df2 = d[2];
    const float hp0 = hp[0], hp1 = hp[1], hp2 = hp[2], hp3 = hp[3], hp4 = hp[4];

    const float nrm = fmaxf(sqrtf(df0*df0 + df1*df1 + df2*df2), 1e-7f);
    const float inv = __fdividef(1.0f, nrm);

    float l[D_IN];
    l[0] = hp0; l[1] = hp1; l[2] = hp2; l[3] = hp3; l[4] = hp4;
    l[5] = temp[t];
    l[6] = df0 * inv; l[7] = df1 * inv; l[8] = df2 * inv;

    // ---- layer 0: (9 -> 32), gated tanh*tanh ----
    float sa[HID], sb[HID];
    #pragma unroll
    for (int j = 0; j < HID; ++j) { sa[j] = ba0[j]; sb[j] = bb0[j]; }
    #pragma unroll
    for (int i = 0; i < D_IN; ++i) {
        const float li = l[i];
        #pragma unroll
        for (int j = 0; j < HID; ++j) {
            sa[j] = fmaf(li, Wa0[i*HID + j], sa[j]);
            sb[j] = fmaf(li, Wb0[i*HID + j], sb[j]);
        }
    }
    float g[HID];
    #pragma unroll
    for (int j = 0; j < HID; ++j) g[j] = fast_tanh(sa[j]) * fast_tanh(sb[j]);

    // ---- layer 1: (32 -> 32), gated tanh*tanh ----
    #pragma unroll
    for (int j = 0; j < HID; ++j) { sa[j] = ba1[j]; sb[j] = bb1[j]; }
    #pragma unroll
    for (int i = 0; i < HID; ++i) {
        const float gi = g[i];
        #pragma unroll
        for (int j = 0; j < HID; ++j) {
            sa[j] = fmaf(gi, Wa1[i*HID + j], sa[j]);
            sb[j] = fmaf(gi, Wb1[i*HID + j], sb[j]);
        }
    }
    #pragma unroll
    for (int j = 0; j < HID; ++j) g[j] = fast_tanh(sa[j]) * fast_tanh(sb[j]);

    // ---- heads ----
    float pa = b_alpha[0], pb = b_beta[0], pg = b_gamma[0];
    float pc0 = b_c[0], pc1 = b_c[1], pc2 = b_c[2], pc3 = b_c[3], pc4 = b_c[4];
    #pragma unroll
    for (int j = 0; j < HID; ++j) {
        const float gv = g[j];
        pa  = fmaf(gv, W_alpha[j],  pa);
        pb  = fmaf(gv, W_beta[j],   pb);
        pg  = fmaf(gv, W_gamma[j],  pg);
        pc0 = fmaf(gv, W_c[j*5 + 0], pc0);
        pc1 = fmaf(gv, W_c[j*5 + 1], pc1);
        pc2 = fmaf(gv, W_c[j*5 + 2], pc2);
        pc3 = fmaf(gv, W_c[j*5 + 3], pc3);
        pc4 = fmaf(gv, W_c[j*5 + 4], pc4);
    }
    const float alpha = __expf(pa);
    const float beta  = __expf(pb);
    const float gamma = __expf(pg);

    const float zarg = -(alpha * fabsf(df0) + beta * df1 + gamma * fabsf(df2));
    const float z    = 1.0f - __expf(zarg);
    const float omz  = 1.0f - z;

    const float c0 = fast_tanh(pc0), c1 = fast_tanh(pc1), c2 = fast_tanh(pc2),
                c3 = fast_tanh(pc3), c4 = fast_tanh(pc4);

    const float hn0 = omz * hp0 + z * c0;
    const float hn1 = omz * hp1 + z * c1;
    const float hn2 = omz * hp2 + z * c2;
    const float hn3 = omz * hp3 + z * c3;
    const float hn4 = omz * hp4 + z * c4;

    float* out_h = out + (size_t)t * 5;
    out_h[0] = hn0; out_h[1] = hn1; out_h[2] = hn2; out_h[3] = hn3; out_h[4] = hn4;

    const float sig = hn0*W_out[0] + hn1*W_out[1] + hn2*W_out[2] + hn3*W_out[3] + hn4*W_out[4];
    out[(size_t)N_TOK * 5 + t] = sig;
}

extern "C" void kernel_launch(void* const* d_in, const int* in_sizes, int n_in,
                              void* d_out, int out_size, void* d_ws, size_t ws_size,
                              hipStream_t stream) {
    const float* h_prev  = (const float*)d_in[0];
    const float* dx      = (const float*)d_in[1];
    const float* Wa0     = (const float*)d_in[2];
    const float* ba0     = (const float*)d_in[3];
    const float* Wb0     = (const float*)d_in[4];
    const float* bb0     = (const float*)d_in[5];
    const float* Wa1     = (const float*)d_in[6];
    const float* ba1     = (const float*)d_in[7];
    const float* Wb1     = (const float*)d_in[8];
    const float* bb1     = (const float*)d_in[9];
    const float* W_alpha = (const float*)d_in[10];
    const float* b_alpha = (const float*)d_in[11];
    const float* W_beta  = (const float*)d_in[12];
    const float* b_beta  = (const float*)d_in[13];
    const float* W_gamma = (const float*)d_in[14];
    const float* b_gamma = (const float*)d_in[15];
    const float* W_c     = (const float*)d_in[16];
    const float* b_c     = (const float*)d_in[17];
    const float* W_out   = (const float*)d_in[18];
    float* out = (float*)d_out;

    // temp_seq scratch: prefer d_ws; fall back to the sigma region of d_out
    // (safe: each msc_kernel thread reads temp[t] before its only write to that slot,
    //  and every store transitively depends on that load).
    float* temp = (ws_size >= (size_t)N_TOK * sizeof(float))
                      ? (float*)d_ws
                      : out + (size_t)N_TOK * 5;

    cumsum_kernel<<<B_DIM, 1024, 0, stream>>>(dx, temp);
    msc_kernel<<<N_TOK / 256, 256, 0, stream>>>(
        h_prev, dx, temp,
        Wa0, ba0, Wb0, bb0, Wa1, ba1, Wb1, bb1,
        W_alpha, b_alpha, W_beta, b_beta, W_gamma, b_gamma,
        W_c, b_c, W_out, out);
}

// Round 2
// 166.053 us; speedup vs baseline: 1.1287x; 1.1287x over previous
//
#include <hip/hip_runtime.h>

#define B_DIM    128
#define S_DIM    4096
#define N_TOK    (B_DIM * S_DIM)
#define HID      32
#define D_IN     9
#define CHUNK    256                 // tokens per msc block == scan chunk
#define N_CHUNK  (N_TOK / CHUNK)     // 2048
#define CPB      (S_DIM / CHUNK)     // 16 chunks per batch

// Cross-kernel scratch (rewritten fully on every kernel_launch call).
__device__ float g_chunksums[N_CHUNK];
__device__ float g_offsets[N_CHUNK];   // exclusive chunk prefix + init_temp

// tanh(x) = 1 - 2/(exp2(2*log2e*x)+1); clamp keeps exp2 in range (tanh(9)~1.0f)
__device__ __forceinline__ float fast_tanh(float x) {
    float xc = fminf(fmaxf(x, -9.0f), 9.0f);
    float e  = __builtin_amdgcn_exp2f(2.885390082f * xc);
    return fmaf(-2.0f, __builtin_amdgcn_rcpf(e + 1.0f), 1.0f);
}

// -------- K1: per-chunk sum of delta_x[..., 2] --------
__global__ __launch_bounds__(256) void chunksum_kernel(const float* __restrict__ dx) {
    const int t    = blockIdx.x * CHUNK + threadIdx.x;
    const int lane = threadIdx.x & 63;
    const int wid  = threadIdx.x >> 6;
    __shared__ float wsum[4];

    float x = dx[(size_t)t * 6 + 2];
    #pragma unroll
    for (int off = 32; off >= 1; off >>= 1) x += __shfl_down(x, off, 64);
    if (lane == 0) wsum[wid] = x;
    __syncthreads();
    if (threadIdx.x == 0)
        g_chunksums[blockIdx.x] = wsum[0] + wsum[1] + wsum[2] + wsum[3];
}

// -------- K2: exclusive scan of chunk sums per batch, seeded with init_temp --------
__global__ __launch_bounds__(128) void offsets_kernel(const float* __restrict__ dx) {
    const int b = threadIdx.x;   // one thread per batch, single block of 128
    float run = dx[(size_t)b * S_DIM * 6 + 5];   // init_temp = delta_x[b,0,5]
    #pragma unroll
    for (int c = 0; c < CPB; ++c) {
        g_offsets[b * CPB + c] = run;
        run += g_chunksums[b * CPB + c];
    }
}

// -------- K3: per-token MLP + gate, with fused within-chunk inclusive scan --------
__global__ __launch_bounds__(256) void msc_kernel(
    const float* __restrict__ h_prev, const float* __restrict__ dx,
    const float* __restrict__ Wa0, const float* __restrict__ ba0,
    const float* __restrict__ Wb0, const float* __restrict__ bb0,
    const float* __restrict__ Wa1, const float* __restrict__ ba1,
    const float* __restrict__ Wb1, const float* __restrict__ bb1,
    const float* __restrict__ W_alpha, const float* __restrict__ b_alpha,
    const float* __restrict__ W_beta,  const float* __restrict__ b_beta,
    const float* __restrict__ W_gamma, const float* __restrict__ b_gamma,
    const float* __restrict__ W_c,     const float* __restrict__ b_c,
    const float* __restrict__ W_out,
    float* __restrict__ out)
{
    const int tid  = threadIdx.x;
    const int t    = blockIdx.x * CHUNK + tid;
    const int lane = tid & 63;
    const int wid  = tid >> 6;
    __shared__ float wsum[4];

    const float* hp = h_prev + (size_t)t * 5;
    const float* d  = dx     + (size_t)t * 6;

    const float df0 = d[0], df1 = d[1], df2 = d[2];
    const float hp0 = hp[0], hp1 = hp[1], hp2 = hp[2], hp3 = hp[3], hp4 = hp[4];

    // ---- fused inclusive scan of df2 within the chunk ----
    float x = df2;
    #pragma unroll
    for (int off = 1; off < 64; off <<= 1) {
        float y = __shfl_up(x, off, 64);
        if (lane >= off) x += y;
    }
    if (lane == 63) wsum[wid] = x;
    __syncthreads();
    float pre = g_offsets[blockIdx.x];   // uniform: exclusive chunk prefix + init_temp
    #pragma unroll
    for (int w = 0; w < 3; ++w)
        if (w < wid) pre += wsum[w];
    const float temp_t = pre + x;        // inclusive cumsum + init_temp

    const float nrm = fmaxf(sqrtf(df0*df0 + df1*df1 + df2*df2), 1e-7f);
    const float inv = __builtin_amdgcn_rcpf(nrm);

    float l[D_IN];
    l[0] = hp0; l[1] = hp1; l[2] = hp2; l[3] = hp3; l[4] = hp4;
    l[5] = temp_t;
    l[6] = df0 * inv; l[7] = df1 * inv; l[8] = df2 * inv;

    // ---- layer 0: (9 -> 32), gated tanh*tanh ----
    float sa[HID], sb[HID];
    #pragma unroll
    for (int j = 0; j < HID; ++j) { sa[j] = ba0[j]; sb[j] = bb0[j]; }
    #pragma unroll
    for (int i = 0; i < D_IN; ++i) {
        const float li = l[i];
        #pragma unroll
        for (int j = 0; j < HID; ++j) {
            sa[j] = fmaf(li, Wa0[i*HID + j], sa[j]);
            sb[j] = fmaf(li, Wb0[i*HID + j], sb[j]);
        }
    }
    float g[HID];
    #pragma unroll
    for (int j = 0; j < HID; ++j) g[j] = fast_tanh(sa[j]) * fast_tanh(sb[j]);

    // ---- layer 1: (32 -> 32), gated tanh*tanh ----
    #pragma unroll
    for (int j = 0; j < HID; ++j) { sa[j] = ba1[j]; sb[j] = bb1[j]; }
    #pragma unroll
    for (int i = 0; i < HID; ++i) {
        const float gi = g[i];
        #pragma unroll
        for (int j = 0; j < HID; ++j) {
            sa[j] = fmaf(gi, Wa1[i*HID + j], sa[j]);
            sb[j] = fmaf(gi, Wb1[i*HID + j], sb[j]);
        }
    }
    #pragma unroll
    for (int j = 0; j < HID; ++j) g[j] = fast_tanh(sa[j]) * fast_tanh(sb[j]);

    // ---- heads ----
    float pa = b_alpha[0], pb = b_beta[0], pg = b_gamma[0];
    float pc0 = b_c[0], pc1 = b_c[1], pc2 = b_c[2], pc3 = b_c[3], pc4 = b_c[4];
    #pragma unroll
    for (int j = 0; j < HID; ++j) {
        const float gv = g[j];
        pa  = fmaf(gv, W_alpha[j],  pa);
        pb  = fmaf(gv, W_beta[j],   pb);
        pg  = fmaf(gv, W_gamma[j],  pg);
        pc0 = fmaf(gv, W_c[j*5 + 0], pc0);
        pc1 = fmaf(gv, W_c[j*5 + 1], pc1);
        pc2 = fmaf(gv, W_c[j*5 + 2], pc2);
        pc3 = fmaf(gv, W_c[j*5 + 3], pc3);
        pc4 = fmaf(gv, W_c[j*5 + 4], pc4);
    }
    const float alpha = __expf(pa);
    const float beta  = __expf(pb);
    const float gamma = __expf(pg);

    const float zarg = -(alpha * fabsf(df0) + beta * df1 + gamma * fabsf(df2));
    const float z    = 1.0f - __expf(zarg);
    const float omz  = 1.0f - z;

    const float c0 = fast_tanh(pc0), c1 = fast_tanh(pc1), c2 = fast_tanh(pc2),
                c3 = fast_tanh(pc3), c4 = fast_tanh(pc4);

    const float hn0 = omz * hp0 + z * c0;
    const float hn1 = omz * hp1 + z * c1;
    const float hn2 = omz * hp2 + z * c2;
    const float hn3 = omz * hp3 + z * c3;
    const float hn4 = omz * hp4 + z * c4;

    float* out_h = out + (size_t)t * 5;
    out_h[0] = hn0; out_h[1] = hn1; out_h[2] = hn2; out_h[3] = hn3; out_h[4] = hn4;

    const float sig = hn0*W_out[0] + hn1*W_out[1] + hn2*W_out[2] + hn3*W_out[3] + hn4*W_out[4];
    out[(size_t)N_TOK * 5 + t] = sig;
}

extern "C" void kernel_launch(void* const* d_in, const int* in_sizes, int n_in,
                              void* d_out, int out_size, void* d_ws, size_t ws_size,
                              hipStream_t stream) {
    const float* h_prev  = (const float*)d_in[0];
    const float* dx      = (const float*)d_in[1];
    const float* Wa0     = (const float*)d_in[2];
    const float* ba0     = (const float*)d_in[3];
    const float* Wb0     = (const float*)d_in[4];
    const float* bb0     = (const float*)d_in[5];
    const float* Wa1     = (const float*)d_in[6];
    const float* ba1     = (const float*)d_in[7];
    const float* Wb1     = (const float*)d_in[8];
    const float* bb1     = (const float*)d_in[9];
    const float* W_alpha = (const float*)d_in[10];
    const float* b_alpha = (const float*)d_in[11];
    const float* W_beta  = (const float*)d_in[12];
    const float* b_beta  = (const float*)d_in[13];
    const float* W_gamma = (const float*)d_in[14];
    const float* b_gamma = (const float*)d_in[15];
    const float* W_c     = (const float*)d_in[16];
    const float* b_c     = (const float*)d_in[17];
    const float* W_out   = (const float*)d_in[18];
    float* out = (float*)d_out;

    chunksum_kernel<<<N_CHUNK, CHUNK, 0, stream>>>(dx);
    offsets_kernel<<<1, B_DIM, 0, stream>>>(dx);
    msc_kernel<<<N_CHUNK, CHUNK, 0, stream>>>(
        h_prev, dx,
        Wa0, ba0, Wb0, bb0, Wa1, ba1, Wb1, bb1,
        W_alpha, b_alpha, W_beta, b_beta, W_gamma, b_gamma,
        W_c, b_c, W_out, out);
}

// Round 3
// 137.348 us; speedup vs baseline: 1.3646x; 1.2090x over previous
//
#include <hip/hip_runtime.h>

#define B_DIMC   128
#define S_DIMC   4096
#define N_TOK    (B_DIMC * S_DIMC)
#define CHUNK    256                 // tokens per msc block == scan chunk
#define N_CHUNK  (N_TOK / CHUNK)     // 2048
#define CPB      (S_DIMC / CHUNK)    // 16 chunks per batch

typedef __attribute__((ext_vector_type(8))) short  short8;   // 8 bf16 (4 VGPR) MFMA A/B frag
typedef __attribute__((ext_vector_type(4))) float  floatx4;  // MFMA C/D frag
typedef __attribute__((ext_vector_type(4))) int    intx4;

__device__ float g_chunksums[N_CHUNK];

__device__ __forceinline__ unsigned short f2bf(float f) {
    unsigned u = __builtin_bit_cast(unsigned, f);
    u = (u + 0x7FFFu + ((u >> 16) & 1u)) >> 16;   // round-to-nearest-even
    return (unsigned short)u;
}
__device__ __forceinline__ int packbf(float a, float b) {
    return (int)f2bf(a) | ((int)f2bf(b) << 16);
}
// tanh(x) = 1 - 2/(exp2(2*log2e*x)+1)
__device__ __forceinline__ float fast_tanh(float x) {
    float xc = fminf(fmaxf(x, -9.0f), 9.0f);
    float e  = __builtin_amdgcn_exp2f(2.885390082f * xc);
    return fmaf(-2.0f, __builtin_amdgcn_rcpf(e + 1.0f), 1.0f);
}

// -------- K1: per-chunk sum of delta_x[..., 2] --------
__global__ __launch_bounds__(256) void chunksum_kernel(const float* __restrict__ dx) {
    const int t    = blockIdx.x * CHUNK + threadIdx.x;
    const int lane = threadIdx.x & 63;
    const int wid  = threadIdx.x >> 6;
    __shared__ float wsum[4];
    float x = dx[(size_t)t * 6 + 2];
    #pragma unroll
    for (int off = 32; off >= 1; off >>= 1) x += __shfl_down(x, off, 64);
    if (lane == 0) wsum[wid] = x;
    __syncthreads();
    if (threadIdx.x == 0)
        g_chunksums[blockIdx.x] = wsum[0] + wsum[1] + wsum[2] + wsum[3];
}

// head weight element for column n, contraction index k
__device__ __forceinline__ float head_w(int n, int k,
                                        const float* Wal, const float* Wbe,
                                        const float* Wga, const float* Wc) {
    if (n == 0) return Wal[k];
    if (n == 1) return Wbe[k];
    if (n == 2) return Wga[k];
    if (n < 8)  return Wc[k * 5 + (n - 3)];
    return 0.0f;
}

// -------- K2: MFMA token-parallel MLP with fused scan --------
__global__ __launch_bounds__(256) void msc_kernel(
    const float* __restrict__ h_prev, const float* __restrict__ dx,
    const float* __restrict__ Wa0, const float* __restrict__ ba0,
    const float* __restrict__ Wb0, const float* __restrict__ bb0,
    const float* __restrict__ Wa1, const float* __restrict__ ba1,
    const float* __restrict__ Wb1, const float* __restrict__ bb1,
    const float* __restrict__ W_alpha, const float* __restrict__ b_alpha,
    const float* __restrict__ W_beta,  const float* __restrict__ b_beta,
    const float* __restrict__ W_gamma, const float* __restrict__ b_gamma,
    const float* __restrict__ W_c,     const float* __restrict__ b_c,
    const float* __restrict__ W_out,
    float* __restrict__ out)
{
    // LDS: B-operands (block-shared) + per-wave A zones. Rows padded to 40 bf16
    // (80 B, 16B-aligned, 2-way-max bank pattern on b128 frag reads = free).
    __shared__ __align__(16) short sW[4][32][40];   // [a0,b0,a1,b1][col n][k] bf16
    __shared__ __align__(16) short sWh[16][40];     // head  [col n][k] bf16
    __shared__ __align__(16) short sA[4][64][40];   // per-wave activations [tok][k]
    __shared__ __align__(16) float sTemps[4][64];   // per-wave temp_seq (fp32!)
    __shared__ float sBias[16];
    __shared__ float sWsum[4];

    const int tid  = threadIdx.x;
    const int w    = tid >> 6;
    const int lane = tid & 63;
    const int n    = lane & 15;
    const int quad = lane >> 4;
    const int t    = blockIdx.x * CHUNK + tid;

    // ---- per-token global loads ----
    const float* hp = h_prev + (size_t)t * 5;
    const float* d  = dx     + (size_t)t * 6;
    const float hp0 = hp[0], hp1 = hp[1], hp2 = hp[2], hp3 = hp[3], hp4 = hp[4];
    const float df0 = d[0], df1 = d[1], df2 = d[2];

    // ---- chunk offset: init_temp + sum of preceding chunk sums in this batch ----
    const int batch = blockIdx.x / CPB;
    const int cib   = blockIdx.x % CPB;
    float coff = dx[(size_t)batch * S_DIMC * 6 + 5];
    #pragma unroll
    for (int c = 0; c < CPB - 1; ++c)
        if (c < cib) coff += g_chunksums[batch * CPB + c];

    // ---- per-lane fp32 epilogue weights (uniform-ish, L2-cached) ----
    float w5a[2], w5b[2], bA0[2], bB0[2], bA1[2], bB1[2];
    #pragma unroll
    for (int nt = 0; nt < 2; ++nt) {
        const int col = nt * 16 + n;
        w5a[nt] = Wa0[5 * 32 + col];  w5b[nt] = Wb0[5 * 32 + col];
        bA0[nt] = ba0[col];           bB0[nt] = bb0[col];
        bA1[nt] = ba1[col];           bB1[nt] = bb1[col];
    }

    // ---- wave-level inclusive scan of df2 ----
    float x = df2;
    #pragma unroll
    for (int off = 1; off < 64; off <<= 1) {
        float y = __shfl_up(x, off, 64);
        if (lane >= off) x += y;
    }
    if (lane == 63) sWsum[w] = x;

    // ---- write layer0 A row: [h(5), 0(temp folded to C), dir(3), 0...] ----
    const float nrm = fmaxf(sqrtf(df0*df0 + df1*df1 + df2*df2), 1e-7f);
    const float inv = __builtin_amdgcn_rcpf(nrm);
    {
        int* arow = (int*)&sA[w][lane][0];
        intx4 v0 = { packbf(hp0, hp1), packbf(hp2, hp3),
                     packbf(hp4, 0.0f), packbf(df0*inv, df1*inv) };
        intx4 v1 = { packbf(df2*inv, 0.0f), 0, 0, 0 };
        intx4 z  = { 0, 0, 0, 0 };
        *(intx4*)&arow[0]  = v0;
        *(intx4*)&arow[4]  = v1;
        *(intx4*)&arow[8]  = z;
        *(intx4*)&arow[12] = z;
    }

    // ---- cooperative B-operand build (bf16, [col][k], invalid k zeroed) ----
    #pragma unroll
    for (int m = 0; m < 4; ++m) {
        const float* Wsrc = (m == 0) ? Wa0 : (m == 1) ? Wb0 : (m == 2) ? Wa1 : Wb1;
        const bool l0 = (m < 2);
        #pragma unroll
        for (int dd = tid; dd < 512; dd += 256) {
            const int col = dd >> 4, kd = dd & 15, k0 = kd * 2, k1 = k0 + 1;
            float v0, v1;
            if (l0) {
                v0 = (k0 < 9 && k0 != 5) ? Wsrc[k0 * 32 + col] : 0.0f;
                v1 = (k1 < 9 && k1 != 5) ? Wsrc[k1 * 32 + col] : 0.0f;
            } else {
                v0 = Wsrc[k0 * 32 + col];
                v1 = Wsrc[k1 * 32 + col];
            }
            ((int*)&sW[m][col][0])[kd] = packbf(v0, v1);
        }
    }
    {   // head B: 16 cols x 32 k, one dword per thread
        const int hn = tid >> 4, kd = tid & 15, k0 = kd * 2;
        const float v0 = head_w(hn, k0,     W_alpha, W_beta, W_gamma, W_c);
        const float v1 = head_w(hn, k0 + 1, W_alpha, W_beta, W_gamma, W_c);
        ((int*)&sWh[hn][0])[kd] = packbf(v0, v1);
    }
    if (tid < 16) {
        sBias[tid] = (tid == 0) ? b_alpha[0] : (tid == 1) ? b_beta[0]
                   : (tid == 2) ? b_gamma[0] : (tid < 8) ? b_c[tid - 3] : 0.0f;
    }

    __syncthreads();

    // ---- temp_seq (fp32, stays out of bf16 path) ----
    float pre = coff;
    if (w > 0) pre += sWsum[0];
    if (w > 1) pre += sWsum[1];
    if (w > 2) pre += sWsum[2];
    const float temp_t = pre + x;
    sTemps[w][lane] = temp_t;

    // ---- load B fragments to registers (reused across all 4 M-tiles) ----
    short8 Ba0f[2], Bb0f[2], Ba1f[2], Bb1f[2], Bhf;
    #pragma unroll
    for (int nt = 0; nt < 2; ++nt) {
        const int col = nt * 16 + n;
        Ba0f[nt] = *(const short8*)&sW[0][col][quad * 8];
        Bb0f[nt] = *(const short8*)&sW[1][col][quad * 8];
        Ba1f[nt] = *(const short8*)&sW[2][col][quad * 8];
        Bb1f[nt] = *(const short8*)&sW[3][col][quad * 8];
    }
    Bhf = *(const short8*)&sWh[n][quad * 8];
    const float hbias = sBias[n];

    // ---- layer 0: C-init = bias + temp*W[5][n] (fp32), MFMA, gate, write G1 ----
    #pragma unroll
    for (int mt = 0; mt < 4; ++mt) {
        const short8  Af = *(const short8*)&sA[w][mt * 16 + n][quad * 8];
        const floatx4 tv = *(const floatx4*)&sTemps[w][mt * 16 + quad * 4];
        #pragma unroll
        for (int nt = 0; nt < 2; ++nt) {
            floatx4 Ca, Cb;
            #pragma unroll
            for (int r = 0; r < 4; ++r) {
                Ca[r] = fmaf(tv[r], w5a[nt], bA0[nt]);
                Cb[r] = fmaf(tv[r], w5b[nt], bB0[nt]);
            }
            Ca = __builtin_amdgcn_mfma_f32_16x16x32_bf16(Af, Ba0f[nt], Ca, 0, 0, 0);
            Cb = __builtin_amdgcn_mfma_f32_16x16x32_bf16(Af, Bb0f[nt], Cb, 0, 0, 0);
            #pragma unroll
            for (int r = 0; r < 4; ++r) {
                const float gv = fast_tanh(Ca[r]) * fast_tanh(Cb[r]);
                sA[w][mt * 16 + quad * 4 + r][nt * 16 + n] = (short)f2bf(gv);
            }
        }
    }

    // ---- layer 1 ----
    #pragma unroll
    for (int mt = 0; mt < 4; ++mt) {
        const short8 Af = *(const short8*)&sA[w][mt * 16 + n][quad * 8];
        #pragma unroll
        for (int nt = 0; nt < 2; ++nt) {
            floatx4 Ca = { bA1[nt], bA1[nt], bA1[nt], bA1[nt] };
            floatx4 Cb = { bB1[nt], bB1[nt], bB1[nt], bB1[nt] };
            Ca = __builtin_amdgcn_mfma_f32_16x16x32_bf16(Af, Ba1f[nt], Ca, 0, 0, 0);
            Cb = __builtin_amdgcn_mfma_f32_16x16x32_bf16(Af, Bb1f[nt], Cb, 0, 0, 0);
            #pragma unroll
            for (int r = 0; r < 4; ++r) {
                const float gv = fast_tanh(Ca[r]) * fast_tanh(Cb[r]);
                sA[w][mt * 16 + quad * 4 + r][nt * 16 + n] = (short)f2bf(gv);
            }
        }
    }

    // ---- heads: prefetch all A-frags, then MFMA + fp32 transpose via LDS ----
    short8 Ah[4];
    #pragma unroll
    for (int mt = 0; mt < 4; ++mt)
        Ah[mt] = *(const short8*)&sA[w][mt * 16 + n][quad * 8];
    __syncthreads();   // ordering fence: short-typed reads above vs float stores below

    float* hc = (float*)&sA[w][0][0];   // [tok][12 dwords] fp32, fits in zone
    #pragma unroll
    for (int mt = 0; mt < 4; ++mt) {
        floatx4 C = { hbias, hbias, hbias, hbias };
        C = __builtin_amdgcn_mfma_f32_16x16x32_bf16(Ah[mt], Bhf, C, 0, 0, 0);
        if (n < 8) {
            #pragma unroll
            for (int r = 0; r < 4; ++r)
                hc[(mt * 16 + quad * 4 + r) * 12 + n] = C[r];
        }
    }

    const floatx4 h0v = *(const floatx4*)&hc[lane * 12];      // pa, pb, pg, pc0
    const floatx4 h1v = *(const floatx4*)&hc[lane * 12 + 4];  // pc1..pc4

    // ---- per-token epilogue ----
    const float alpha = __expf(h0v[0]);
    const float beta  = __expf(h0v[1]);
    const float gamma = __expf(h0v[2]);
    const float z     = 1.0f - __expf(-(alpha * fabsf(df0) + beta * df1 + gamma * fabsf(df2)));
    const float omz   = 1.0f - z;

    const float c0 = fast_tanh(h0v[3]), c1 = fast_tanh(h1v[0]), c2 = fast_tanh(h1v[1]),
                c3 = fast_tanh(h1v[2]), c4 = fast_tanh(h1v[3]);

    const float hn0 = omz * hp0 + z * c0;
    const float hn1 = omz * hp1 + z * c1;
    const float hn2 = omz * hp2 + z * c2;
    const float hn3 = omz * hp3 + z * c3;
    const float hn4 = omz * hp4 + z * c4;

    float* out_h = out + (size_t)t * 5;
    out_h[0] = hn0; out_h[1] = hn1; out_h[2] = hn2; out_h[3] = hn3; out_h[4] = hn4;
    out[(size_t)N_TOK * 5 + t] =
        hn0 * W_out[0] + hn1 * W_out[1] + hn2 * W_out[2] + hn3 * W_out[3] + hn4 * W_out[4];
}

extern "C" void kernel_launch(void* const* d_in, const int* in_sizes, int n_in,
                              void* d_out, int out_size, void* d_ws, size_t ws_size,
                              hipStream_t stream) {
    const float* h_prev  = (const float*)d_in[0];
    const float* dx      = (const float*)d_in[1];
    const float* Wa0     = (const float*)d_in[2];
    const float* ba0     = (const float*)d_in[3];
    const float* Wb0     = (const float*)d_in[4];
    const float* bb0     = (const float*)d_in[5];
    const float* Wa1     = (const float*)d_in[6];
    const float* ba1     = (const float*)d_in[7];
    const float* Wb1     = (const float*)d_in[8];
    const float* bb1     = (const float*)d_in[9];
    const float* W_alpha = (const float*)d_in[10];
    const float* b_alpha = (const float*)d_in[11];
    const float* W_beta  = (const float*)d_in[12];
    const float* b_beta  = (const float*)d_in[13];
    const float* W_gamma = (const float*)d_in[14];
    const float* b_gamma = (const float*)d_in[15];
    const float* W_c     = (const float*)d_in[16];
    const float* b_c     = (const float*)d_in[17];
    const float* W_out   = (const float*)d_in[18];
    float* out = (float*)d_out;

    chunksum_kernel<<<N_CHUNK, CHUNK, 0, stream>>>(dx);
    msc_kernel<<<N_CHUNK, CHUNK, 0, stream>>>(
        h_prev, dx,
        Wa0, ba0, Wb0, bb0, Wa1, ba1, Wb1, bb1,
        W_alpha, b_alpha, W_beta, b_beta, W_gamma, b_gamma,
        W_c, b_c, W_out, out);
}